// Round 4
// baseline (406.238 us; speedup 1.0000x reference)
//
#include <hip/hip_runtime.h>
#include <hip/hip_bf16.h>
#include <stdint.h>

#define M_DIM 8192   // rows of x / out
#define K_DIM 4096   // inner dim
#define N_DIM 4096   // cols of out = rows of W

typedef int intx4  __attribute__((ext_vector_type(4)));
typedef int intx16 __attribute__((ext_vector_type(16)));

// ---------------------------------------------------------------------------
// Fused conversion:
//   blocks [0, 8192):      one block per row of x -> per-row absmax-quant i8
//   blocks [8192, 16384):  w fp32 -> sign as i8, 8 elems/thread
// ---------------------------------------------------------------------------
__global__ void cvt_fused_i8_kernel(const float* __restrict__ x,
                                    const float* __restrict__ w,
                                    signed char* __restrict__ xb,
                                    signed char* __restrict__ wb,
                                    float* __restrict__ row_scale) {
    const int b   = blockIdx.x;
    const int tid = threadIdx.x;
    if (b < M_DIM) {
        // quantize one 4096-element row of x; fully coalesced loads
        __shared__ float wmax[4];
        const float* xr = x + (size_t)b * K_DIM;
        float4 v[4];
#pragma unroll
        for (int i = 0; i < 4; ++i)
            v[i] = *(const float4*)(xr + tid * 4 + i * 1024);

        float am = 0.f;
#pragma unroll
        for (int i = 0; i < 4; ++i) {
            am = fmaxf(am, fabsf(v[i].x)); am = fmaxf(am, fabsf(v[i].y));
            am = fmaxf(am, fabsf(v[i].z)); am = fmaxf(am, fabsf(v[i].w));
        }
#pragma unroll
        for (int off = 32; off > 0; off >>= 1)
            am = fmaxf(am, __shfl_xor(am, off));
        if ((tid & 63) == 0) wmax[tid >> 6] = am;
        __syncthreads();
        am = fmaxf(fmaxf(wmax[0], wmax[1]), fmaxf(wmax[2], wmax[3]));
        am = fmaxf(am, 1e-30f);

        const float inv = 127.f / am;
#pragma unroll
        for (int i = 0; i < 4; ++i) {
            union { signed char c[4]; uint32_t u; } r;
            const float* vf = (const float*)&v[i];
#pragma unroll
            for (int k = 0; k < 4; ++k) {
                int q = (int)rintf(vf[k] * inv);
                q = q > 127 ? 127 : (q < -127 ? -127 : q);
                r.c[k] = (signed char)q;
            }
            *(uint32_t*)(xb + (size_t)b * K_DIM + tid * 4 + i * 1024) = r.u;
        }
        if (tid == 0) row_scale[b] = am * (1.f / 127.f);
    } else {
        // sign(w) -> i8, 8 elems/thread
        size_t t = ((size_t)(b - M_DIM) * blockDim.x + tid) * 8;
        float4 a = *(const float4*)(w + t);
        float4 c = *(const float4*)(w + t + 4);
        union { signed char s[8]; uint2 u; } r;
        r.s[0] = (a.x > 0.f) - (a.x < 0.f); r.s[1] = (a.y > 0.f) - (a.y < 0.f);
        r.s[2] = (a.z > 0.f) - (a.z < 0.f); r.s[3] = (a.w > 0.f) - (a.w < 0.f);
        r.s[4] = (c.x > 0.f) - (c.x < 0.f); r.s[5] = (c.y > 0.f) - (c.y < 0.f);
        r.s[6] = (c.z > 0.f) - (c.z < 0.f); r.s[7] = (c.w > 0.f) - (c.w < 0.f);
        *(uint2*)(wb + t) = r.u;
    }
}

__device__ __forceinline__ void gld_lds16(const void* g, void* l) {
    __builtin_amdgcn_global_load_lds(
        (const __attribute__((address_space(1))) void*)g,
        (__attribute__((address_space(3))) void*)l,
        16, 0, 0);
}

// ---------------------------------------------------------------------------
// i8 GEMM, round-4: OCCUPANCY lever (r1-r3 invariance showed 1 block/CU =
// 2 waves/SIMD barrier-locked cannot fill ~60% bubbles; m114: overlap needs
// independent waves).
//   Block tile 256x128, BK=64, 512 thr = 8 waves (4M x 2N), wave C = 64x64
//   via mfma_i32_32x32x32_i8 (acc[2][2] x intx16 = 64 acc regs).
//   LDS ring-3: 3 x (16K A + 8K B) = 72 KiB  ->  2 blocks/CU, 4 waves/SIMD.
//   Two blocks are barrier-INDEPENDENT: one block's MFMA covers the other's
//   LDS bursts / vmcnt waits / barriers / prologue+epilogue.
// Schedule per K-tile (single phase, 2 barriers):
//   { 8 ds_read_b128 (both k-steps) + 3 gld_lds (tile t+2);
//     s_barrier; lgkmcnt(0); setprio(1); 8 MFMA; setprio(0);
//     counted vmcnt(3) [never 0 mid-loop]; s_barrier }
// Ring-3 hazards: stage at t writes slot (t+2)%3 = slot read at t-1, whose
// reads drained (lgkm0 + barrier) before t's stage issues. Reads of slot t%3
// need loads staged at t-2: vmcnt(3) at t-1 boundary guarantees residency.
// Swizzle (unchanged algebra from r3, verified passing): LDS[row][c^f(row)],
// f(row)=((row>>1)&3)^(((row>>4)&1)<<1); write side reduces to
// (lane>>3)&3 ^ (wave&1)<<1 for ALL three staged panels (A-half0, A-half1, B);
// read side fsw=((r5>>1)&3)^(((r5>>4)&1)<<1).
// ---------------------------------------------------------------------------
__global__ void __launch_bounds__(512, 4)
gemm_i8_kernel(const signed char* __restrict__ A,
               const signed char* __restrict__ B,
               const float* __restrict__ bias,
               const float* __restrict__ scale,
               const float* __restrict__ row_scale,
               float* __restrict__ out) {
    __shared__ __attribute__((aligned(16))) signed char sA[3][256 * 64];
    __shared__ __attribute__((aligned(16))) signed char sB[3][128 * 64];

    const int tid  = threadIdx.x;
    const int lane = tid & 63;
    const int wave = tid >> 6;   // 0..7
    const int wm = wave >> 1;    // 0..3 : 64-row slice
    const int wn = wave & 1;     // 0..1 : 64-col slice
    const int r5 = lane & 31;
    const int hi = lane >> 5;

    // XCD-bijective swizzle: 1024 blocks = 8 XCDs x 128; n-fast within XCD
    const int bid = blockIdx.x;
    const int swz = (bid & 7) * 128 + (bid >> 3);
    const int rowBase = (swz >> 5) * 256;   // 32 m-blocks
    const int colBase = (swz & 31) * 128;   // 32 n-blocks

    // ---- staging: linear LDS dest, pre-swizzled global chunk ----
    const int sc   = (lane & 3) ^ ((lane >> 3) & 3) ^ ((wave & 1) << 1);
    const int srow = wave * 16 + (lane >> 2);
    const signed char* gA0 = A + (size_t)(rowBase + srow) * K_DIM + sc * 16;
    const signed char* gA1 = gA0 + (size_t)128 * K_DIM;
    const signed char* gB0 = B + (size_t)(colBase + srow) * K_DIM + sc * 16;
    const int ldsA0 = wave * 1024;
    const int ldsA1 = 8192 + wave * 1024;
    const int ldsB0 = wave * 1024;

    // ---- fragment read offsets (row=lane&31, chunk=hi+2*kstep, XORed) ----
    const int fsw = ((r5 >> 1) & 3) ^ (((r5 >> 4) & 1) << 1);
    const int ck0 = ((hi + 0) ^ fsw) * 16;    // k-step 0
    const int ck1 = ((hi + 2) ^ fsw) * 16;    // k-step 1
    const int aOff = (wm * 64 + r5) * 64;     // + mt*2048
    const int bOff = (wn * 64 + r5) * 64;     // + nt*2048

    intx16 acc[2][2] = {};

    // ---- prologue: stage tiles 0,1 (6 glds/wave) ----
#pragma unroll
    for (int s = 0; s < 2; ++s) {
        const size_t kg = (size_t)s * 64;
        gld_lds16(gA0 + kg, &sA[s][ldsA0]);
        gld_lds16(gA1 + kg, &sA[s][ldsA1]);
        gld_lds16(gB0 + kg, &sB[s][ldsB0]);
    }
    asm volatile("s_waitcnt vmcnt(3)" ::: "memory");  // tile 0 landed
    __builtin_amdgcn_s_barrier();

    int sr = 0;          // read slot   (t % 3)
    int sw = 2;          // stage slot  ((t+2) % 3)
    for (int t = 0; t < 64; ++t) {
        const signed char* sAb = sA[sr];
        const signed char* sBb = sB[sr];

        // ---- issue all 8 fragment reads + stage tile t+2 ----
        intx4 fa[2], fb[2], oa[2], ob[2];
#pragma unroll
        for (int mt = 0; mt < 2; ++mt) {
            fa[mt] = *(const intx4*)(sAb + aOff + mt * 2048 + ck0);
            oa[mt] = *(const intx4*)(sAb + aOff + mt * 2048 + ck1);
        }
#pragma unroll
        for (int nt = 0; nt < 2; ++nt) {
            fb[nt] = *(const intx4*)(sBb + bOff + nt * 2048 + ck0);
            ob[nt] = *(const intx4*)(sBb + bOff + nt * 2048 + ck1);
        }
        if (t <= 61) {
            const size_t kg = (size_t)(t + 2) * 64;
            gld_lds16(gA0 + kg, &sA[sw][ldsA0]);
            gld_lds16(gA1 + kg, &sA[sw][ldsA1]);
            gld_lds16(gB0 + kg, &sB[sw][ldsB0]);
        }
        __builtin_amdgcn_sched_barrier(0);
        __builtin_amdgcn_s_barrier();
        asm volatile("s_waitcnt lgkmcnt(0)" ::: "memory");
        __builtin_amdgcn_sched_barrier(0);

        // ---- 8 MFMA (both k-steps) ----
        __builtin_amdgcn_s_setprio(1);
#pragma unroll
        for (int mt = 0; mt < 2; ++mt)
#pragma unroll
            for (int nt = 0; nt < 2; ++nt)
                acc[mt][nt] = __builtin_amdgcn_mfma_i32_32x32x32_i8(
                    fa[mt], fb[nt], acc[mt][nt], 0, 0, 0);
#pragma unroll
        for (int mt = 0; mt < 2; ++mt)
#pragma unroll
            for (int nt = 0; nt < 2; ++nt)
                acc[mt][nt] = __builtin_amdgcn_mfma_i32_32x32x32_i8(
                    oa[mt], ob[nt], acc[mt][nt], 0, 0, 0);
        __builtin_amdgcn_s_setprio(0);
        __builtin_amdgcn_sched_barrier(0);

        // ---- K-tile boundary: counted vmcnt (tile t+1 resident) ----
        if (t <= 61)      asm volatile("s_waitcnt vmcnt(3)" ::: "memory");
        else if (t == 62) asm volatile("s_waitcnt vmcnt(0)" ::: "memory");
        __builtin_amdgcn_s_barrier();

        sr = (sr == 2) ? 0 : sr + 1;
        sw = (sw == 2) ? 0 : sw + 1;
    }

    // ---- epilogue: 32x32 C/D layout col=lane&31, row=(reg&3)+8*(reg>>2)+4*hi
    const float s = scale[0];
#pragma unroll
    for (int nt = 0; nt < 2; ++nt) {
        const int gcol = colBase + wn * 64 + nt * 32 + r5;
        const float bv = bias[gcol];
#pragma unroll
        for (int mt = 0; mt < 2; ++mt) {
#pragma unroll
            for (int q = 0; q < 4; ++q) {
                const int row0 = rowBase + wm * 64 + mt * 32 + q * 8 + hi * 4;
                const float4 rs4 = *(const float4*)(row_scale + row0);
                const float rs[4] = {rs4.x, rs4.y, rs4.z, rs4.w};
#pragma unroll
                for (int r = 0; r < 4; ++r)
                    __builtin_nontemporal_store(
                        s * ((float)acc[mt][nt][q * 4 + r] * rs[r] + bv),
                        out + (size_t)(row0 + r) * N_DIM + gcol);
            }
        }
    }
}

// slow but correct fp32 fallback (only if workspace is too small)
__global__ void fallback_kernel(const float* __restrict__ x,
                                const float* __restrict__ w,
                                const float* __restrict__ bias,
                                const float* __restrict__ scale,
                                float* __restrict__ out) {
    int col = blockIdx.x * 64 + (threadIdx.x & 63);
    int row = blockIdx.y * 4 + (threadIdx.x >> 6);
    const float* xr = x + (size_t)row * K_DIM;
    const float* wr = w + (size_t)col * K_DIM;
    float acc = 0.f;
    for (int k = 0; k < K_DIM; k += 4) {
        float4 a = *(const float4*)(xr + k);
        float4 b = *(const float4*)(wr + k);
        acc += a.x * (b.x > 0.f ? 1.f : (b.x < 0.f ? -1.f : 0.f));
        acc += a.y * (b.y > 0.f ? 1.f : (b.y < 0.f ? -1.f : 0.f));
        acc += a.z * (b.z > 0.f ? 1.f : (b.z < 0.f ? -1.f : 0.f));
        acc += a.w * (b.w > 0.f ? 1.f : (b.w < 0.f ? -1.f : 0.f));
    }
    out[(size_t)row * N_DIM + col] = scale[0] * (acc + bias[col]);
}

extern "C" void kernel_launch(void* const* d_in, const int* in_sizes, int n_in,
                              void* d_out, int out_size, void* d_ws, size_t ws_size,
                              hipStream_t stream) {
    const float* x     = (const float*)d_in[0];
    const float* w     = (const float*)d_in[1];
    const float* bias  = (const float*)d_in[2];
    const float* scale = (const float*)d_in[3];
    float* out = (float*)d_out;

    const size_t xb_bytes = (size_t)M_DIM * K_DIM;          // 32 MiB
    const size_t wb_bytes = (size_t)N_DIM * K_DIM;          // 16 MiB
    const size_t need = xb_bytes + wb_bytes + M_DIM * sizeof(float);

    if (ws_size >= need) {
        signed char* xb = (signed char*)d_ws;
        signed char* wb = xb + xb_bytes;
        float* row_scale = (float*)(wb + wb_bytes);
        const unsigned w_blocks = (unsigned)((size_t)N_DIM * K_DIM / 8 / 256); // 8192
        cvt_fused_i8_kernel<<<dim3(M_DIM + w_blocks), 256, 0, stream>>>(
            x, w, xb, wb, row_scale);
        gemm_i8_kernel<<<dim3((M_DIM / 256) * (N_DIM / 128)), 512, 0, stream>>>(
            xb, wb, bias, scale, row_scale, out);
    } else {
        dim3 grid(N_DIM / 64, M_DIM / 4);
        fallback_kernel<<<grid, 256, 0, stream>>>(x, w, bias, scale, out);
    }
}

// Round 6
// 396.657 us; speedup vs baseline: 1.0242x; 1.0242x over previous
//
#include <hip/hip_runtime.h>
#include <hip/hip_bf16.h>
#include <stdint.h>

#define M_DIM 8192   // rows of x / out
#define K_DIM 4096   // inner dim
#define N_DIM 4096   // cols of out = rows of W

typedef int intx4  __attribute__((ext_vector_type(4)));
typedef int intx16 __attribute__((ext_vector_type(16)));

// ---------------------------------------------------------------------------
// Fused conversion:
//   blocks [0, 8192):      one block per row of x -> per-row absmax-quant i8
//   blocks [8192, 16384):  w fp32 -> sign as i8, 8 elems/thread
// ---------------------------------------------------------------------------
__global__ void cvt_fused_i8_kernel(const float* __restrict__ x,
                                    const float* __restrict__ w,
                                    signed char* __restrict__ xb,
                                    signed char* __restrict__ wb,
                                    float* __restrict__ row_scale) {
    const int b   = blockIdx.x;
    const int tid = threadIdx.x;
    if (b < M_DIM) {
        // quantize one 4096-element row of x; fully coalesced loads
        __shared__ float wmax[4];
        const float* xr = x + (size_t)b * K_DIM;
        float4 v[4];
#pragma unroll
        for (int i = 0; i < 4; ++i)
            v[i] = *(const float4*)(xr + tid * 4 + i * 1024);

        float am = 0.f;
#pragma unroll
        for (int i = 0; i < 4; ++i) {
            am = fmaxf(am, fabsf(v[i].x)); am = fmaxf(am, fabsf(v[i].y));
            am = fmaxf(am, fabsf(v[i].z)); am = fmaxf(am, fabsf(v[i].w));
        }
#pragma unroll
        for (int off = 32; off > 0; off >>= 1)
            am = fmaxf(am, __shfl_xor(am, off));
        if ((tid & 63) == 0) wmax[tid >> 6] = am;
        __syncthreads();
        am = fmaxf(fmaxf(wmax[0], wmax[1]), fmaxf(wmax[2], wmax[3]));
        am = fmaxf(am, 1e-30f);

        const float inv = 127.f / am;
#pragma unroll
        for (int i = 0; i < 4; ++i) {
            union { signed char c[4]; uint32_t u; } r;
            const float* vf = (const float*)&v[i];
#pragma unroll
            for (int k = 0; k < 4; ++k) {
                int q = (int)rintf(vf[k] * inv);
                q = q > 127 ? 127 : (q < -127 ? -127 : q);
                r.c[k] = (signed char)q;
            }
            *(uint32_t*)(xb + (size_t)b * K_DIM + tid * 4 + i * 1024) = r.u;
        }
        if (tid == 0) row_scale[b] = am * (1.f / 127.f);
    } else {
        // sign(w) -> i8, 8 elems/thread
        size_t t = ((size_t)(b - M_DIM) * blockDim.x + tid) * 8;
        float4 a = *(const float4*)(w + t);
        float4 c = *(const float4*)(w + t + 4);
        union { signed char s[8]; uint2 u; } r;
        r.s[0] = (a.x > 0.f) - (a.x < 0.f); r.s[1] = (a.y > 0.f) - (a.y < 0.f);
        r.s[2] = (a.z > 0.f) - (a.z < 0.f); r.s[3] = (a.w > 0.f) - (a.w < 0.f);
        r.s[4] = (c.x > 0.f) - (c.x < 0.f); r.s[5] = (c.y > 0.f) - (c.y < 0.f);
        r.s[6] = (c.z > 0.f) - (c.z < 0.f); r.s[7] = (c.w > 0.f) - (c.w < 0.f);
        *(uint2*)(wb + t) = r.u;
    }
}

__device__ __forceinline__ void gld_lds16(const void* g, void* l) {
    __builtin_amdgcn_global_load_lds(
        (const __attribute__((address_space(1))) void*)g,
        (__attribute__((address_space(3))) void*)l,
        16, 0, 0);
}

// ---------------------------------------------------------------------------
// i8 GEMM round-5 (resubmit; round-5 bench was an infra failure, no signal):
// WITHIN-WAVE ILP (intra-tile k-split).
// r2-r4 counters prove LDS-port time and MFMA-pipe time serialize chip-wide
// (period = port + pipe in every config): fair port arbitration keeps waves
// in lockstep, so inter-wave overlap never develops. Fix: give each wave its
// OWN overlap -- issue all 12 fragment reads (both k-steps) at tile top;
// cluster A (8 MFMA, k-step0) waits on counted lgkmcnt(6) only, k-step1's 6
// reads drain UNDER cluster A; cluster B finds lgkmcnt(0) already satisfied.
//
// Geometry = r3's balanced point (port ~= pipe): 256x256 tile, BK=64,
// 512 thr = 8 waves (2M x 4N), wave C = 128x64 via mfma_i32_32x32x32_i8
// (acc[4][2] x intx16 = 128 regs, frags 48 regs, 2 waves/SIMD).
// LDS ring-3: 3 x (16K A + 16K B) = 96 KiB, prefetch distance 2.
// Per tile: ONE barrier + ONE counted vmcnt(4) (never 0 mid-loop).
// Hazards: glds at t write slot (t+2)%3 == slot (t-1)%3 -- its reads fully
// drained (consumed by t-1's MFMAs) before the t-1 exit barrier; reads at t
// of slot t%3 staged at t-2, residency by vmcnt(4) at t-1 exit.
//
// Swizzle: verified r3/r4 algebra. LDS[row][c^f(row)],
// f(row)=((row>>1)&3)^(((row>>4)&1)<<1); write side (lane>>3)&3^(wave&1)<<1,
// read side ((r5>>1)&3)^(((r5>>4)&1)<<1).
// ---------------------------------------------------------------------------
__global__ void __launch_bounds__(512, 2)
gemm_i8_kernel(const signed char* __restrict__ A,
               const signed char* __restrict__ B,
               const float* __restrict__ bias,
               const float* __restrict__ scale,
               const float* __restrict__ row_scale,
               float* __restrict__ out) {
    __shared__ __attribute__((aligned(16))) signed char sA[3][256 * 64];
    __shared__ __attribute__((aligned(16))) signed char sB[3][256 * 64];

    const int tid  = threadIdx.x;
    const int lane = tid & 63;
    const int wave = tid >> 6;   // 0..7
    const int wm = wave >> 2;    // 0..1 : 128-row half
    const int wn = wave & 3;     // 0..3 : 64-col slice
    const int r5 = lane & 31;
    const int hi = lane >> 5;

    // XCD-bijective swizzle: 512 blocks = 8 XCDs x 64; n-fast within XCD
    const int bid = blockIdx.x;
    const int swz = (bid & 7) * 64 + (bid >> 3);
    const int rowBase = (swz >> 4) * 256;
    const int colBase = (swz & 15) * 256;

    // ---- staging: linear LDS dest, pre-swizzled global chunk ----
    const int sc   = (lane & 3) ^ ((lane >> 3) & 3) ^ ((wave & 1) << 1);
    const int srow = wave * 16 + (lane >> 2);
    const signed char* gA0 = A + (size_t)(rowBase + srow) * K_DIM + sc * 16;
    const signed char* gA1 = gA0 + (size_t)128 * K_DIM;
    const signed char* gB0 = B + (size_t)(colBase + srow) * K_DIM + sc * 16;
    const signed char* gB1 = gB0 + (size_t)128 * K_DIM;
    const int ldsR0 = wave * 1024;
    const int ldsR1 = 8192 + wave * 1024;

    // ---- fragment read offsets (row=lane&31, chunk=hi+2*kstep, XORed) ----
    const int fsw = ((r5 >> 1) & 3) ^ (((r5 >> 4) & 1) << 1);
    const int ckE = ((hi + 0) ^ fsw) * 16;    // k-step 0: logical chunks {0,1}
    const int ckO = ((hi + 2) ^ fsw) * 16;    // k-step 1: logical chunks {2,3}
    const int aOff = (wm * 128 + r5) * 64;    // + mt*2048
    const int bOff = (wn * 64 + r5) * 64;     // + nt*2048

    intx16 acc[4][2] = {};

    // ---- prologue: stage tiles 0,1 (8 glds/wave) ----
#pragma unroll
    for (int s = 0; s < 2; ++s) {
        const size_t kg = (size_t)s * 64;
        gld_lds16(gA0 + kg, &sA[s][ldsR0]);
        gld_lds16(gA1 + kg, &sA[s][ldsR1]);
        gld_lds16(gB0 + kg, &sB[s][ldsR0]);
        gld_lds16(gB1 + kg, &sB[s][ldsR1]);
    }
    asm volatile("s_waitcnt vmcnt(4)" ::: "memory");  // tile 0 landed
    __builtin_amdgcn_s_barrier();

    int sr = 0;          // read slot   (t % 3)
    int sw = 2;          // stage slot  ((t+2) % 3)
    for (int t = 0; t < 64; ++t) {
        const signed char* sAb = sA[sr];
        const signed char* sBb = sB[sr];

        // ---- k-step 0 reads FIRST (cluster A waits only on these 6) ----
        intx4 fa[4], fb[2];
#pragma unroll
        for (int mt = 0; mt < 4; ++mt)
            fa[mt] = *(const intx4*)(sAb + aOff + mt * 2048 + ckE);
#pragma unroll
        for (int nt = 0; nt < 2; ++nt)
            fb[nt] = *(const intx4*)(sBb + bOff + nt * 2048 + ckE);
        __builtin_amdgcn_sched_barrier(0);

        // ---- k-step 1 reads + stage tile t+2: drain UNDER cluster A ----
        intx4 oa[4], ob[2];
#pragma unroll
        for (int mt = 0; mt < 4; ++mt)
            oa[mt] = *(const intx4*)(sAb + aOff + mt * 2048 + ckO);
#pragma unroll
        for (int nt = 0; nt < 2; ++nt)
            ob[nt] = *(const intx4*)(sBb + bOff + nt * 2048 + ckO);
        if (t <= 61) {
            const size_t kg = (size_t)(t + 2) * 64;
            gld_lds16(gA0 + kg, &sA[sw][ldsR0]);
            gld_lds16(gA1 + kg, &sA[sw][ldsR1]);
            gld_lds16(gB0 + kg, &sB[sw][ldsR0]);
            gld_lds16(gB1 + kg, &sB[sw][ldsR1]);
        }
        __builtin_amdgcn_sched_barrier(0);

        // ---- cluster A: 8 MFMA k-step 0 (compiler emits lgkmcnt(6)) ----
        __builtin_amdgcn_s_setprio(1);
#pragma unroll
        for (int mt = 0; mt < 4; ++mt)
#pragma unroll
            for (int nt = 0; nt < 2; ++nt)
                acc[mt][nt] = __builtin_amdgcn_mfma_i32_32x32x32_i8(
                    fa[mt], fb[nt], acc[mt][nt], 0, 0, 0);
        __builtin_amdgcn_s_setprio(0);
        __builtin_amdgcn_sched_barrier(0);

        // ---- cluster B: 8 MFMA k-step 1 (lgkm already drained) ----
        __builtin_amdgcn_s_setprio(1);
#pragma unroll
        for (int mt = 0; mt < 4; ++mt)
#pragma unroll
            for (int nt = 0; nt < 2; ++nt)
                acc[mt][nt] = __builtin_amdgcn_mfma_i32_32x32x32_i8(
                    oa[mt], ob[nt], acc[mt][nt], 0, 0, 0);
        __builtin_amdgcn_s_setprio(0);
        __builtin_amdgcn_sched_barrier(0);

        // ---- tile boundary: counted vmcnt (t+1 resident), ONE barrier ----
        if (t <= 61)      asm volatile("s_waitcnt vmcnt(4)" ::: "memory");
        else if (t == 62) asm volatile("s_waitcnt vmcnt(0)" ::: "memory");
        __builtin_amdgcn_s_barrier();

        sr = (sr == 2) ? 0 : sr + 1;
        sw = (sw == 2) ? 0 : sw + 1;
    }

    // ---- epilogue: 32x32 C/D layout col=lane&31, row=(reg&3)+8*(reg>>2)+4*hi
    const float s = scale[0];
#pragma unroll
    for (int nt = 0; nt < 2; ++nt) {
        const int gcol = colBase + wn * 64 + nt * 32 + r5;
        const float bv = bias[gcol];
#pragma unroll
        for (int mt = 0; mt < 4; ++mt) {
#pragma unroll
            for (int q = 0; q < 4; ++q) {
                const int row0 = rowBase + wm * 128 + mt * 32 + q * 8 + hi * 4;
                const float4 rs4 = *(const float4*)(row_scale + row0);
                const float rs[4] = {rs4.x, rs4.y, rs4.z, rs4.w};
#pragma unroll
                for (int r = 0; r < 4; ++r)
                    __builtin_nontemporal_store(
                        s * ((float)acc[mt][nt][q * 4 + r] * rs[r] + bv),
                        out + (size_t)(row0 + r) * N_DIM + gcol);
            }
        }
    }
}

// slow but correct fp32 fallback (only if workspace is too small)
__global__ void fallback_kernel(const float* __restrict__ x,
                                const float* __restrict__ w,
                                const float* __restrict__ bias,
                                const float* __restrict__ scale,
                                float* __restrict__ out) {
    int col = blockIdx.x * 64 + (threadIdx.x & 63);
    int row = blockIdx.y * 4 + (threadIdx.x >> 6);
    const float* xr = x + (size_t)row * K_DIM;
    const float* wr = w + (size_t)col * K_DIM;
    float acc = 0.f;
    for (int k = 0; k < K_DIM; k += 4) {
        float4 a = *(const float4*)(xr + k);
        float4 b = *(const float4*)(wr + k);
        acc += a.x * (b.x > 0.f ? 1.f : (b.x < 0.f ? -1.f : 0.f));
        acc += a.y * (b.y > 0.f ? 1.f : (b.y < 0.f ? -1.f : 0.f));
        acc += a.z * (b.z > 0.f ? 1.f : (b.z < 0.f ? -1.f : 0.f));
        acc += a.w * (b.w > 0.f ? 1.f : (b.w < 0.f ? -1.f : 0.f));
    }
    out[(size_t)row * N_DIM + col] = scale[0] * (acc + bias[col]);
}

extern "C" void kernel_launch(void* const* d_in, const int* in_sizes, int n_in,
                              void* d_out, int out_size, void* d_ws, size_t ws_size,
                              hipStream_t stream) {
    const float* x     = (const float*)d_in[0];
    const float* w     = (const float*)d_in[1];
    const float* bias  = (const float*)d_in[2];
    const float* scale = (const float*)d_in[3];
    float* out = (float*)d_out;

    const size_t xb_bytes = (size_t)M_DIM * K_DIM;          // 32 MiB
    const size_t wb_bytes = (size_t)N_DIM * K_DIM;          // 16 MiB
    const size_t need = xb_bytes + wb_bytes + M_DIM * sizeof(float);

    if (ws_size >= need) {
        signed char* xb = (signed char*)d_ws;
        signed char* wb = xb + xb_bytes;
        float* row_scale = (float*)(wb + wb_bytes);
        const unsigned w_blocks = (unsigned)((size_t)N_DIM * K_DIM / 8 / 256); // 8192
        cvt_fused_i8_kernel<<<dim3(M_DIM + w_blocks), 256, 0, stream>>>(
            x, w, xb, wb, row_scale);
        gemm_i8_kernel<<<dim3((M_DIM / 256) * (N_DIM / 256)), 512, 0, stream>>>(
            xb, wb, bias, scale, row_scale, out);
    } else {
        dim3 grid(N_DIM / 64, M_DIM / 4);
        fallback_kernel<<<grid, 256, 0, stream>>>(x, w, bias, scale, out);
    }
}